// Round 4
// baseline (125.531 us; speedup 1.0000x reference)
//
#include <hip/hip_runtime.h>
#include <cstdint>

#define BB   16
#define NN   1024
#define FIN  128
#define FOUT 64
#define ALPHA_S 0.2f
#define LOG2E 1.44269504f

typedef float    f32x4 __attribute__((ext_vector_type(4)));
typedef _Float16 half8 __attribute__((ext_vector_type(8)));
typedef _Float16 half4 __attribute__((ext_vector_type(4)));
typedef __fp16   pk2   __attribute__((ext_vector_type(2)));
typedef __fp16   pk4   __attribute__((ext_vector_type(4)));
typedef __fp16   pk8   __attribute__((ext_vector_type(8)));

__device__ __forceinline__ float fast_exp2(float x){
  float r; asm("v_exp_f32 %0, %1" : "=v"(r) : "v"(x)); return r;
}

// ---------------------------------------------------------------------------
// Kernel 1 (MFMA): h = inp @ W via f16 hi/lo 3-term MFMA (rel err ~2^-22);
// s1 = (h.a1)*log2e, s2 = (h.a2)*log2e  (log2-domain fold for k_attn's exp2);
// hT (f16, hi only) in layout hT[b][j>>5][f][j&31].
// ---------------------------------------------------------------------------
__global__ __launch_bounds__(256) void k_proj(const float* __restrict__ inp,
                                              const float* __restrict__ W,
                                              const float* __restrict__ a,
                                              _Float16* __restrict__ hT,
                                              float* __restrict__ s1,
                                              float* __restrict__ s2){
  __shared__ float red1[4][16];
  __shared__ float red2[4][16];
  const int t = threadIdx.x;
  const int w = t >> 6, lane = t & 63;
  const int m16 = lane & 15, g = lane >> 4;
  const int i0 = blockIdx.x * 16;          // global row tile (16 rows)
  const int b  = i0 >> 10;
  const int j0 = i0 & 1023;
  const int c0 = w * 16;                   // this wave's col tile

  const float* arow = inp + (size_t)(i0 + m16) * FIN;

  f32x4 acc = {0.f, 0.f, 0.f, 0.f};
  #pragma unroll
  for (int kk = 0; kk < 4; ++kk){
    const int kbase = kk * 32 + g * 8;
    float4 av0 = *(const float4*)(arow + kbase);
    float4 av1 = *(const float4*)(arow + kbase + 4);
    const float av[8] = {av0.x, av0.y, av0.z, av0.w, av1.x, av1.y, av1.z, av1.w};
    half8 ah, al;
    #pragma unroll
    for (int j = 0; j < 8; ++j){
      _Float16 h = (_Float16)av[j];
      ah[j] = h;
      al[j] = (_Float16)(av[j] - (float)h);
    }
    half8 bh, bl;
    #pragma unroll
    for (int j = 0; j < 8; ++j){
      float wv = W[(kbase + j) * FOUT + c0 + m16];   // L1-hot (W = 32 KB)
      _Float16 h = (_Float16)wv;
      bh[j] = h;
      bl[j] = (_Float16)(wv - (float)h);
    }
    acc = __builtin_amdgcn_mfma_f32_16x16x32_f16(ah, bh, acc, 0, 0, 0);
    acc = __builtin_amdgcn_mfma_f32_16x16x32_f16(ah, bl, acc, 0, 0, 0);
    acc = __builtin_amdgcn_mfma_f32_16x16x32_f16(al, bh, acc, 0, 0, 0);
  }

  // ---- s1/s2 partials: sum over this wave's 16 cols, rows g*4+q ----
  const float a1c = a[c0 + m16];
  const float a2c = a[FOUT + c0 + m16];
  f32x4 p1, p2;
  #pragma unroll
  for (int q = 0; q < 4; ++q){ p1[q] = acc[q] * a1c; p2[q] = acc[q] * a2c; }
  #pragma unroll
  for (int off = 1; off < 16; off <<= 1){
    #pragma unroll
    for (int q = 0; q < 4; ++q){
      p1[q] += __shfl_xor(p1[q], off, 64);
      p2[q] += __shfl_xor(p2[q], off, 64);
    }
  }
  if (m16 == 0){
    #pragma unroll
    for (int q = 0; q < 4; ++q){
      red1[w][g * 4 + q] = p1[q];
      red2[w][g * 4 + q] = p2[q];
    }
  }

  // ---- hT store (hi only): f = c0+m16, j = i0 + g*4 + q ----
  half4 hv;
  #pragma unroll
  for (int q = 0; q < 4; ++q) hv[q] = (_Float16)acc[q];
  size_t idx = (size_t)b * 65536 + (size_t)(j0 >> 5) * 2048
             + (size_t)(c0 + m16) * 32 + (size_t)(j0 & 31) + (size_t)g * 4;
  *(half4*)(hT + idx) = hv;

  __syncthreads();
  if (t < 16){
    s1[i0 + t] = (red1[0][t] + red1[1][t] + red1[2][t] + red1[3][t]) * LOG2E;
    s2[i0 + t] = (red2[0][t] + red2[1][t] + red2[2][t] + red2[3][t]) * LOG2E;
  }
}

// ---------------------------------------------------------------------------
// Kernel 2: fused GAT attention, 4-chunk software-pipelined, <=128 VGPR
// (4 waves/SIMD).  1024 blocks x 256 thr.  Block = (batch, 16-row tile).
// Wave w owns j-range [w*256, w*256+256), processed as 4 chunks of 64 cols
// with flash-style online max (exact).  adj burst double-buffered so HBM
// latency hides under VALU+MFMA.  s2 read directly from global (L1/L2-hot).
// KEY LAYOUT FACT: A-frag row held by a lane is m16, but C-frag rows are
// g*4+q.  So psum rescale uses this lane's (row m16) factor, while acc
// rescale must fetch row (g*4+q)'s factor via __shfl from lane g*4+q
// (factors are uniform across the 4 g-lanes of each m16).
// ---------------------------------------------------------------------------
__global__ __launch_bounds__(256, 4) void k_attn(const int* __restrict__ adj,
                                                 const _Float16* __restrict__ hT,
                                                 const float* __restrict__ s1,
                                                 const float* __restrict__ s2,
                                                 float* __restrict__ out){
  __shared__ float redmax[4][16];
  __shared__ float redl[4][16];
  __shared__ float csum[4][1088];       // 4 x (16 rows x 68-pad) ~17 KB

  const int t = threadIdx.x;
  const int w = t >> 6, lane = t & 63;
  const int m16 = lane & 15, g = lane >> 4;
  const int b  = blockIdx.x >> 6;
  const int i0 = (blockIdx.x & 63) * 16;
  const int jb = w * 256;

  const int*   arow = adj + ((size_t)(b * NN + i0 + m16)) * NN + jb + g * 8;
  const float* s2p  = s2 + b * NN + jb + g * 8;
  const float  s1i  = s1[b * NN + i0 + m16];
  const _Float16* bhp = hT + (size_t)b * 65536 + (size_t)(w * 8) * 2048
                      + (size_t)m16 * 32 + (size_t)g * 8;

  // ---- prologue: adj burst for chunk 0 (double-buffered thereafter) ----
  int4 Abuf[2][4];
  Abuf[0][0] = *(const int4*)(arow + 0);
  Abuf[0][1] = *(const int4*)(arow + 4);
  Abuf[0][2] = *(const int4*)(arow + 32);
  Abuf[0][3] = *(const int4*)(arow + 36);

  f32x4 acc0 = {0,0,0,0}, acc1 = {0,0,0,0}, acc2 = {0,0,0,0}, acc3 = {0,0,0,0};
  float psA = 0.f, psB = 0.f;
  float mold = -3.0e38f;

  #pragma unroll
  for (int cc = 0; cc < 4; ++cc){
    const int ph = cc & 1;
    // prefetch next chunk's adj burst (HBM) before this chunk's compute
    if (cc < 3){
      const int np = ph ^ 1;
      const int nb = (cc + 1) * 64;
      Abuf[np][0] = *(const int4*)(arow + nb);
      Abuf[np][1] = *(const int4*)(arow + nb + 4);
      Abuf[np][2] = *(const int4*)(arow + nb + 32);
      Abuf[np][3] = *(const int4*)(arow + nb + 36);
    }
    const int cb = cc * 64;
    const float4 S0 = *(const float4*)(s2p + cb);
    const float4 S1 = *(const float4*)(s2p + cb + 4);
    const float4 S2 = *(const float4*)(s2p + cb + 32);
    const float4 S3 = *(const float4*)(s2p + cb + 36);

    // masked scores + chunk max (all for row i0+m16)
    float smv[16];
    float cmax = -3.0e38f;
    {
      const int4 Av0 = Abuf[ph][0], Av1 = Abuf[ph][1];
      const int4 Av2 = Abuf[ph][2], Av3 = Abuf[ph][3];
      float v;
      v = (Av0.x > 0) ? S0.x : -3.0e38f; smv[ 0] = v; cmax = fmaxf(cmax, v);
      v = (Av0.y > 0) ? S0.y : -3.0e38f; smv[ 1] = v; cmax = fmaxf(cmax, v);
      v = (Av0.z > 0) ? S0.z : -3.0e38f; smv[ 2] = v; cmax = fmaxf(cmax, v);
      v = (Av0.w > 0) ? S0.w : -3.0e38f; smv[ 3] = v; cmax = fmaxf(cmax, v);
      v = (Av1.x > 0) ? S1.x : -3.0e38f; smv[ 4] = v; cmax = fmaxf(cmax, v);
      v = (Av1.y > 0) ? S1.y : -3.0e38f; smv[ 5] = v; cmax = fmaxf(cmax, v);
      v = (Av1.z > 0) ? S1.z : -3.0e38f; smv[ 6] = v; cmax = fmaxf(cmax, v);
      v = (Av1.w > 0) ? S1.w : -3.0e38f; smv[ 7] = v; cmax = fmaxf(cmax, v);
      v = (Av2.x > 0) ? S2.x : -3.0e38f; smv[ 8] = v; cmax = fmaxf(cmax, v);
      v = (Av2.y > 0) ? S2.y : -3.0e38f; smv[ 9] = v; cmax = fmaxf(cmax, v);
      v = (Av2.z > 0) ? S2.z : -3.0e38f; smv[10] = v; cmax = fmaxf(cmax, v);
      v = (Av2.w > 0) ? S2.w : -3.0e38f; smv[11] = v; cmax = fmaxf(cmax, v);
      v = (Av3.x > 0) ? S3.x : -3.0e38f; smv[12] = v; cmax = fmaxf(cmax, v);
      v = (Av3.y > 0) ? S3.y : -3.0e38f; smv[13] = v; cmax = fmaxf(cmax, v);
      v = (Av3.z > 0) ? S3.z : -3.0e38f; smv[14] = v; cmax = fmaxf(cmax, v);
      v = (Av3.w > 0) ? S3.w : -3.0e38f; smv[15] = v; cmax = fmaxf(cmax, v);
    }
    cmax = fmaxf(cmax, __shfl_xor(cmax, 16, 64));
    cmax = fmaxf(cmax, __shfl_xor(cmax, 32, 64));   // uniform across g now
    const float xm   = s1i + cmax;
    const float mc   = fmaxf(xm, ALPHA_S * xm);   // leaky, log2 domain
    const float mnew = fmaxf(mold, mc);
    if (cc){                                      // flash rescale (exact)
      const float frv = fast_exp2(mold - mnew);   // factor for row m16
      psA *= frv; psB *= frv;                     // psum is row m16's -> OK
      #pragma unroll
      for (int q = 0; q < 4; ++q){                // acc rows are g*4+q!
        const float frq = __shfl(frv, g * 4 + q, 64);
        acc0[q] *= frq; acc1[q] *= frq; acc2[q] *= frq; acc3[q] *= frq;
      }
    }
    mold = mnew;
    const float s1m = s1i - mnew;
    const float c2  = ALPHA_S * s1i - mnew;

    float p[16];
    #pragma unroll
    for (int u = 0; u < 16; ++u)
      p[u] = fast_exp2(fmaxf(s1m + smv[u], fmaf(ALPHA_S, smv[u], c2)));
    psA += ((p[0] + p[1]) + (p[2] + p[3])) + ((p[4] + p[5]) + (p[6] + p[7]));
    psB += ((p[8] + p[9]) + (p[10] + p[11])) + ((p[12] + p[13]) + (p[14] + p[15]));

    pk2 q0 = __builtin_amdgcn_cvt_pkrtz(p[ 0], p[ 1]);
    pk2 q1 = __builtin_amdgcn_cvt_pkrtz(p[ 2], p[ 3]);
    pk2 q2 = __builtin_amdgcn_cvt_pkrtz(p[ 4], p[ 5]);
    pk2 q3 = __builtin_amdgcn_cvt_pkrtz(p[ 6], p[ 7]);
    pk2 q4 = __builtin_amdgcn_cvt_pkrtz(p[ 8], p[ 9]);
    pk2 q5 = __builtin_amdgcn_cvt_pkrtz(p[10], p[11]);
    pk2 q6 = __builtin_amdgcn_cvt_pkrtz(p[12], p[13]);
    pk2 q7 = __builtin_amdgcn_cvt_pkrtz(p[14], p[15]);
    pk4 l0 = __builtin_shufflevector(q0, q1, 0, 1, 2, 3);
    pk4 l1 = __builtin_shufflevector(q2, q3, 0, 1, 2, 3);
    pk4 l2 = __builtin_shufflevector(q4, q5, 0, 1, 2, 3);
    pk4 l3 = __builtin_shufflevector(q6, q7, 0, 1, 2, 3);
    half8 af0 = __builtin_bit_cast(half8,
                  __builtin_shufflevector(l0, l1, 0, 1, 2, 3, 4, 5, 6, 7));
    half8 af1 = __builtin_bit_cast(half8,
                  __builtin_shufflevector(l2, l3, 0, 1, 2, 3, 4, 5, 6, 7));

    const _Float16* bp0 = bhp + (size_t)(cc * 2) * 2048;
    const _Float16* bp1 = bp0 + 2048;
    half8 b00 = *(const half8*)(bp0);
    half8 b01 = *(const half8*)(bp0 + 512);
    half8 b02 = *(const half8*)(bp0 + 1024);
    half8 b03 = *(const half8*)(bp0 + 1536);
    half8 b10 = *(const half8*)(bp1);
    half8 b11 = *(const half8*)(bp1 + 512);
    half8 b12 = *(const half8*)(bp1 + 1024);
    half8 b13 = *(const half8*)(bp1 + 1536);
    acc0 = __builtin_amdgcn_mfma_f32_16x16x32_f16(af0, b00, acc0, 0, 0, 0);
    acc1 = __builtin_amdgcn_mfma_f32_16x16x32_f16(af0, b01, acc1, 0, 0, 0);
    acc2 = __builtin_amdgcn_mfma_f32_16x16x32_f16(af0, b02, acc2, 0, 0, 0);
    acc3 = __builtin_amdgcn_mfma_f32_16x16x32_f16(af0, b03, acc3, 0, 0, 0);
    acc0 = __builtin_amdgcn_mfma_f32_16x16x32_f16(af1, b10, acc0, 0, 0, 0);
    acc1 = __builtin_amdgcn_mfma_f32_16x16x32_f16(af1, b11, acc1, 0, 0, 0);
    acc2 = __builtin_amdgcn_mfma_f32_16x16x32_f16(af1, b12, acc2, 0, 0, 0);
    acc3 = __builtin_amdgcn_mfma_f32_16x16x32_f16(af1, b13, acc3, 0, 0, 0);
  }

  // ---- epilogue: single barrier; flash-style cross-wave merge ----
  if (g == 0) redmax[w][m16] = mold;
  float psum = psA + psB;
  psum += __shfl_xor(psum, 16, 64);
  psum += __shfl_xor(psum, 32, 64);
  if (g == 0) redl[w][m16] = psum;

  #pragma unroll
  for (int q = 0; q < 4; ++q){                 // C: row = g*4+q, col = c*16+m16
    csum[w][(g * 4 + q) * 68 +  0 + m16] = acc0[q];
    csum[w][(g * 4 + q) * 68 + 16 + m16] = acc1[q];
    csum[w][(g * 4 + q) * 68 + 32 + m16] = acc2[q];
    csum[w][(g * 4 + q) * 68 + 48 + m16] = acc3[q];
  }
  __syncthreads();

  const int r  = t >> 4;                       // 0..15
  const int c4 = (t & 15) * 4;                 // 0..60
  const float m0 = redmax[0][r], m1 = redmax[1][r];
  const float m2 = redmax[2][r], m3 = redmax[3][r];
  const float mg = fmaxf(fmaxf(m0, m1), fmaxf(m2, m3));
  const float f0 = fast_exp2(m0 - mg), f1 = fast_exp2(m1 - mg);
  const float f2 = fast_exp2(m2 - mg), f3 = fast_exp2(m3 - mg);

  f32x4 c0v = *(const f32x4*)&csum[0][r * 68 + c4];
  f32x4 c1v = *(const f32x4*)&csum[1][r * 68 + c4];
  f32x4 c2v = *(const f32x4*)&csum[2][r * 68 + c4];
  f32x4 c3v = *(const f32x4*)&csum[3][r * 68 + c4];
  f32x4 sum;
  #pragma unroll
  for (int u = 0; u < 4; ++u)
    sum[u] = c0v[u] * f0 + c1v[u] * f1 + c2v[u] * f2 + c3v[u] * f3;

  const float l = redl[0][r] * f0 + redl[1][r] * f1
                + redl[2][r] * f2 + redl[3][r] * f3;
  const float linv = (l > 0.f) ? __builtin_amdgcn_rcpf(l) : 0.f;
  f32x4 o;
  #pragma unroll
  for (int u = 0; u < 4; ++u){
    float v = sum[u] * linv;
    o[u] = v > 0.f ? v : __expf(v) - 1.0f;     // ELU (alpha=1)
  }
  *(f32x4*)(out + ((size_t)(b * NN + i0 + r)) * FOUT + c4) = o;
}

extern "C" void kernel_launch(void* const* d_in, const int* in_sizes, int n_in,
                              void* d_out, int out_size, void* d_ws, size_t ws_size,
                              hipStream_t stream) {
  (void)in_sizes; (void)n_in; (void)out_size; (void)ws_size;
  const float* inp = (const float*)d_in[0];   // (16,1024,128) fp32
  const int*   adj = (const int*)d_in[1];     // (16,1024,1024) int32
  const float* W   = (const float*)d_in[2];   // (128,64) fp32
  const float* a   = (const float*)d_in[3];   // (128,1) fp32
  float* outp = (float*)d_out;                // (16,1024,64) fp32

  _Float16* hT = (_Float16*)d_ws;                      // 2 MB (hi only)
  float* s1 = (float*)(hT + (size_t)BB * 65536);       // 64 KB
  float* s2 = s1 + BB * NN;                            // 64 KB

  k_proj<<<BB * NN / 16, 256, 0, stream>>>(inp, W, a, hT, s1, s2);
  k_attn<<<BB * (NN / 16), 256, 0, stream>>>(adj, hT, s1, s2, outp);
}

// Round 5
// 114.603 us; speedup vs baseline: 1.0953x; 1.0953x over previous
//
#include <hip/hip_runtime.h>
#include <cstdint>

#define BB   16
#define NN   1024
#define FIN  128
#define FOUT 64
#define ALPHA_S 0.2f
#define LOG2E 1.44269504f

typedef float    f32x4 __attribute__((ext_vector_type(4)));
typedef _Float16 half8 __attribute__((ext_vector_type(8)));
typedef _Float16 half4 __attribute__((ext_vector_type(4)));
typedef __fp16   pk2   __attribute__((ext_vector_type(2)));
typedef __fp16   pk4   __attribute__((ext_vector_type(4)));
typedef __fp16   pk8   __attribute__((ext_vector_type(8)));

__device__ __forceinline__ float fast_exp2(float x){
  float r; asm("v_exp_f32 %0, %1" : "=v"(r) : "v"(x)); return r;
}

// ---------------------------------------------------------------------------
// Kernel 1 (MFMA): h = inp @ W via f16 hi/lo 3-term MFMA (rel err ~2^-22);
// s1 = (h.a1)*log2e, s2 = (h.a2)*log2e  (log2-domain fold for k_attn's exp2);
// hT (f16, hi only) in layout hT[b][j>>5][f][j&31].
// ---------------------------------------------------------------------------
__global__ __launch_bounds__(256) void k_proj(const float* __restrict__ inp,
                                              const float* __restrict__ W,
                                              const float* __restrict__ a,
                                              _Float16* __restrict__ hT,
                                              float* __restrict__ s1,
                                              float* __restrict__ s2){
  __shared__ float red1[4][16];
  __shared__ float red2[4][16];
  const int t = threadIdx.x;
  const int w = t >> 6, lane = t & 63;
  const int m16 = lane & 15, g = lane >> 4;
  const int i0 = blockIdx.x * 16;          // global row tile (16 rows)
  const int b  = i0 >> 10;
  const int j0 = i0 & 1023;
  const int c0 = w * 16;                   // this wave's col tile

  const float* arow = inp + (size_t)(i0 + m16) * FIN;

  f32x4 acc = {0.f, 0.f, 0.f, 0.f};
  #pragma unroll
  for (int kk = 0; kk < 4; ++kk){
    const int kbase = kk * 32 + g * 8;
    float4 av0 = *(const float4*)(arow + kbase);
    float4 av1 = *(const float4*)(arow + kbase + 4);
    const float av[8] = {av0.x, av0.y, av0.z, av0.w, av1.x, av1.y, av1.z, av1.w};
    half8 ah, al;
    #pragma unroll
    for (int j = 0; j < 8; ++j){
      _Float16 h = (_Float16)av[j];
      ah[j] = h;
      al[j] = (_Float16)(av[j] - (float)h);
    }
    half8 bh, bl;
    #pragma unroll
    for (int j = 0; j < 8; ++j){
      float wv = W[(kbase + j) * FOUT + c0 + m16];   // L1-hot (W = 32 KB)
      _Float16 h = (_Float16)wv;
      bh[j] = h;
      bl[j] = (_Float16)(wv - (float)h);
    }
    acc = __builtin_amdgcn_mfma_f32_16x16x32_f16(ah, bh, acc, 0, 0, 0);
    acc = __builtin_amdgcn_mfma_f32_16x16x32_f16(ah, bl, acc, 0, 0, 0);
    acc = __builtin_amdgcn_mfma_f32_16x16x32_f16(al, bh, acc, 0, 0, 0);
  }

  // ---- s1/s2 partials: sum over this wave's 16 cols, rows g*4+q ----
  const float a1c = a[c0 + m16];
  const float a2c = a[FOUT + c0 + m16];
  f32x4 p1, p2;
  #pragma unroll
  for (int q = 0; q < 4; ++q){ p1[q] = acc[q] * a1c; p2[q] = acc[q] * a2c; }
  #pragma unroll
  for (int off = 1; off < 16; off <<= 1){
    #pragma unroll
    for (int q = 0; q < 4; ++q){
      p1[q] += __shfl_xor(p1[q], off, 64);
      p2[q] += __shfl_xor(p2[q], off, 64);
    }
  }
  if (m16 == 0){
    #pragma unroll
    for (int q = 0; q < 4; ++q){
      red1[w][g * 4 + q] = p1[q];
      red2[w][g * 4 + q] = p2[q];
    }
  }

  // ---- hT store (hi only): f = c0+m16, j = i0 + g*4 + q ----
  half4 hv;
  #pragma unroll
  for (int q = 0; q < 4; ++q) hv[q] = (_Float16)acc[q];
  size_t idx = (size_t)b * 65536 + (size_t)(j0 >> 5) * 2048
             + (size_t)(c0 + m16) * 32 + (size_t)(j0 & 31) + (size_t)g * 4;
  *(half4*)(hT + idx) = hv;

  __syncthreads();
  if (t < 16){
    s1[i0 + t] = (red1[0][t] + red1[1][t] + red1[2][t] + red1[3][t]) * LOG2E;
    s2[i0 + t] = (red2[0][t] + red2[1][t] + red2[2][t] + red2[3][t]) * LOG2E;
  }
}

// ---------------------------------------------------------------------------
// Kernel 2: fused GAT attention, barrier-free main body, low-VGPR variant.
// 1024 blocks x 256 thr = EXACTLY 4 blocks/CU resident (one wavefront-round,
// no tail) under __launch_bounds__(256,4) -> <=128 VGPR, 16 waves/CU.
// Wave w owns j-range [w*256, w*256+256).  Pass 1: 16-int4 adj burst (full
// MLP, proven R2 structure) -> 2-reg bitmask + wave-LOCAL masked max of s2
// (read from LDS).  Pass 2: re-reads s2 from LDS (saves 48 VGPR vs sm[64]),
// p = bit ? exp2(max(s1m+sv, fma(a,sv,c2))) : 0, cvt_pkrtz -> A-frag,
// 4 col-tile MFMAs per kk.  Single barrier; epilogue merges waves
// flash-style by output row r (exact).
// ---------------------------------------------------------------------------
__global__ __launch_bounds__(256, 4) void k_attn(const int* __restrict__ adj,
                                                 const _Float16* __restrict__ hT,
                                                 const float* __restrict__ s1,
                                                 const float* __restrict__ s2,
                                                 float* __restrict__ out){
  __shared__ float s2_s[NN];            // 4 KB
  __shared__ float redmax[4][16];
  __shared__ float redl[4][16];
  __shared__ float csum[4][1088];       // 4 x (16 rows x 68-pad) ~17 KB

  const int t = threadIdx.x;
  const int w = t >> 6, lane = t & 63;
  const int m16 = lane & 15, g = lane >> 4;
  const int b  = blockIdx.x >> 6;
  const int i0 = (blockIdx.x & 63) * 16;
  const int jb = w * 256;

  // stage this wave's s2 chunk (wave-internal lgkmcnt ordering; only this
  // wave reads its chunk, so no barrier needed before the LDS reads)
  *(float4*)&s2_s[jb + lane * 4] = *(const float4*)(s2 + b * NN + jb + lane * 4);

  // ---- adj burst: 16 int4 loads in flight; row i0+m16, cols jb+kk*32+g*8 ----
  const int* arow = adj + ((size_t)(b * NN + i0 + m16)) * NN + jb + g * 8;
  int4 A0[8], A1[8];
  #pragma unroll
  for (int kk = 0; kk < 8; ++kk){
    A0[kk] = *(const int4*)(arow + kk * 32);
    A1[kk] = *(const int4*)(arow + kk * 32 + 4);
  }

  const float s1i = s1[b * NN + i0 + m16];

  // ---- pass 1: bitmask (2 regs) + wave-local masked max of s2 ----
  unsigned mask_lo = 0u, mask_hi = 0u;
  float mxp = -3.0e38f;
  #pragma unroll
  for (int kk = 0; kk < 8; ++kk){
    float4 sA = *(const float4*)&s2_s[jb + kk * 32 + g * 8];
    float4 sB = *(const float4*)&s2_s[jb + kk * 32 + g * 8 + 4];
    unsigned bits = 0u;
    bits |= (A0[kk].x > 0) ? 1u   : 0u;  mxp = fmaxf(mxp, A0[kk].x > 0 ? sA.x : -3.0e38f);
    bits |= (A0[kk].y > 0) ? 2u   : 0u;  mxp = fmaxf(mxp, A0[kk].y > 0 ? sA.y : -3.0e38f);
    bits |= (A0[kk].z > 0) ? 4u   : 0u;  mxp = fmaxf(mxp, A0[kk].z > 0 ? sA.z : -3.0e38f);
    bits |= (A0[kk].w > 0) ? 8u   : 0u;  mxp = fmaxf(mxp, A0[kk].w > 0 ? sA.w : -3.0e38f);
    bits |= (A1[kk].x > 0) ? 16u  : 0u;  mxp = fmaxf(mxp, A1[kk].x > 0 ? sB.x : -3.0e38f);
    bits |= (A1[kk].y > 0) ? 32u  : 0u;  mxp = fmaxf(mxp, A1[kk].y > 0 ? sB.y : -3.0e38f);
    bits |= (A1[kk].z > 0) ? 64u  : 0u;  mxp = fmaxf(mxp, A1[kk].z > 0 ? sB.z : -3.0e38f);
    bits |= (A1[kk].w > 0) ? 128u : 0u;  mxp = fmaxf(mxp, A1[kk].w > 0 ? sB.w : -3.0e38f);
    if (kk < 4) mask_lo |= bits << (kk * 8);
    else        mask_hi |= bits << ((kk - 4) * 8);
  }

  // wave-local row max across the 4 lanes sharing m16 (no cross-wave barrier)
  mxp = fmaxf(mxp, __shfl_xor(mxp, 16, 64));
  mxp = fmaxf(mxp, __shfl_xor(mxp, 32, 64));
  mxp = fmaxf(mxp, -1.0e30f);                 // empty-row safe clamp
  const float xm   = s1i + mxp;
  const float mrow = fmaxf(xm, ALPHA_S * xm); // wave-local max of leaky (log2 dom)
  if (g == 0) redmax[w][m16] = mrow;
  const float s1m = s1i - mrow;
  const float c2  = ALPHA_S * s1i - mrow;

  // ---- pass 2: p from mask + LDS s2 -> 4 col-tile MFMAs (hi only) ----
  f32x4 acc0 = {0,0,0,0}, acc1 = {0,0,0,0}, acc2 = {0,0,0,0}, acc3 = {0,0,0,0};
  float psum = 0.f;
  const _Float16* bhp = hT + (size_t)b * 65536 + (size_t)(w * 8) * 2048
                      + (size_t)m16 * 32 + (size_t)g * 8;

  #pragma unroll
  for (int kk = 0; kk < 8; ++kk){
    float4 sA = *(const float4*)&s2_s[jb + kk * 32 + g * 8];
    float4 sB = *(const float4*)&s2_s[jb + kk * 32 + g * 8 + 4];
    const unsigned bits = (kk < 4) ? (mask_lo >> (kk * 8)) : (mask_hi >> ((kk - 4) * 8));
    const float sv[8] = {sA.x, sA.y, sA.z, sA.w, sB.x, sB.y, sB.z, sB.w};
    float p[8];
    #pragma unroll
    for (int u = 0; u < 8; ++u){
      float e = fast_exp2(fmaxf(s1m + sv[u], fmaf(ALPHA_S, sv[u], c2)));
      p[u] = ((bits >> u) & 1u) ? e : 0.0f;
    }
    psum += ((p[0] + p[1]) + (p[2] + p[3])) + ((p[4] + p[5]) + (p[6] + p[7]));

    pk2 q0 = __builtin_amdgcn_cvt_pkrtz(p[0], p[1]);
    pk2 q1 = __builtin_amdgcn_cvt_pkrtz(p[2], p[3]);
    pk2 q2 = __builtin_amdgcn_cvt_pkrtz(p[4], p[5]);
    pk2 q3 = __builtin_amdgcn_cvt_pkrtz(p[6], p[7]);
    pk4 l0 = __builtin_shufflevector(q0, q1, 0, 1, 2, 3);
    pk4 l1 = __builtin_shufflevector(q2, q3, 0, 1, 2, 3);
    half8 af = __builtin_bit_cast(half8,
                 __builtin_shufflevector(l0, l1, 0, 1, 2, 3, 4, 5, 6, 7));

    half8 b0 = *(const half8*)(bhp + kk * 2048);
    half8 b1 = *(const half8*)(bhp + kk * 2048 + 512);
    half8 b2 = *(const half8*)(bhp + kk * 2048 + 1024);
    half8 b3 = *(const half8*)(bhp + kk * 2048 + 1536);
    acc0 = __builtin_amdgcn_mfma_f32_16x16x32_f16(af, b0, acc0, 0, 0, 0);
    acc1 = __builtin_amdgcn_mfma_f32_16x16x32_f16(af, b1, acc1, 0, 0, 0);
    acc2 = __builtin_amdgcn_mfma_f32_16x16x32_f16(af, b2, acc2, 0, 0, 0);
    acc3 = __builtin_amdgcn_mfma_f32_16x16x32_f16(af, b3, acc3, 0, 0, 0);
  }

  // ---- epilogue: single barrier; flash-style cross-wave merge ----
  psum += __shfl_xor(psum, 16, 64);
  psum += __shfl_xor(psum, 32, 64);
  if (g == 0) redl[w][m16] = psum;

  #pragma unroll
  for (int q = 0; q < 4; ++q){                 // C: row = g*4+q, col = c*16+m16
    csum[w][(g * 4 + q) * 68 +  0 + m16] = acc0[q];
    csum[w][(g * 4 + q) * 68 + 16 + m16] = acc1[q];
    csum[w][(g * 4 + q) * 68 + 32 + m16] = acc2[q];
    csum[w][(g * 4 + q) * 68 + 48 + m16] = acc3[q];
  }
  __syncthreads();

  const int r  = t >> 4;                       // 0..15
  const int c4 = (t & 15) * 4;                 // 0..60
  const float m0 = redmax[0][r], m1 = redmax[1][r];
  const float m2 = redmax[2][r], m3 = redmax[3][r];
  const float mg = fmaxf(fmaxf(m0, m1), fmaxf(m2, m3));
  const float f0 = fast_exp2(m0 - mg), f1 = fast_exp2(m1 - mg);
  const float f2 = fast_exp2(m2 - mg), f3 = fast_exp2(m3 - mg);

  f32x4 c0v = *(const f32x4*)&csum[0][r * 68 + c4];
  f32x4 c1v = *(const f32x4*)&csum[1][r * 68 + c4];
  f32x4 c2v = *(const f32x4*)&csum[2][r * 68 + c4];
  f32x4 c3v = *(const f32x4*)&csum[3][r * 68 + c4];
  f32x4 sum;
  #pragma unroll
  for (int u = 0; u < 4; ++u)
    sum[u] = c0v[u] * f0 + c1v[u] * f1 + c2v[u] * f2 + c3v[u] * f3;

  const float l = redl[0][r] * f0 + redl[1][r] * f1
                + redl[2][r] * f2 + redl[3][r] * f3;
  const float linv = (l > 0.f) ? __builtin_amdgcn_rcpf(l) : 0.f;
  f32x4 o;
  #pragma unroll
  for (int u = 0; u < 4; ++u){
    float v = sum[u] * linv;
    o[u] = v > 0.f ? v : __expf(v) - 1.0f;     // ELU (alpha=1)
  }
  *(f32x4*)(out + ((size_t)(b * NN + i0 + r)) * FOUT + c4) = o;
}

extern "C" void kernel_launch(void* const* d_in, const int* in_sizes, int n_in,
                              void* d_out, int out_size, void* d_ws, size_t ws_size,
                              hipStream_t stream) {
  (void)in_sizes; (void)n_in; (void)out_size; (void)ws_size;
  const float* inp = (const float*)d_in[0];   // (16,1024,128) fp32
  const int*   adj = (const int*)d_in[1];     // (16,1024,1024) int32
  const float* W   = (const float*)d_in[2];   // (128,64) fp32
  const float* a   = (const float*)d_in[3];   // (128,1) fp32
  float* outp = (float*)d_out;                // (16,1024,64) fp32

  _Float16* hT = (_Float16*)d_ws;                      // 2 MB (hi only)
  float* s1 = (float*)(hT + (size_t)BB * 65536);       // 64 KB
  float* s2 = s1 + BB * NN;                            // 64 KB

  k_proj<<<BB * NN / 16, 256, 0, stream>>>(inp, W, a, hT, s1, s2);
  k_attn<<<BB * (NN / 16), 256, 0, stream>>>(adj, hT, s1, s2, outp);
}